// Round 13
// baseline (150.496 us; speedup 1.0000x reference)
//
#include <hip/hip_runtime.h>

#define NN 4096
#define DIM 128
#define TN 128           // q-rows per block (8 waves x 16 rows)
#define TM 64            // m-tile size
#define NSPLIT 16        // split-m factor (atomic combine); grid = 32*16 = 512 = 2/CU
#define NTILES 4         // tiles per block (64 global tiles / 16)

typedef __attribute__((ext_vector_type(8))) short bf16x8;
typedef __attribute__((ext_vector_type(4))) float f32x4;
typedef __attribute__((ext_vector_type(4))) unsigned u32x4;

#define HRS 136                        // Hrow stride (ushorts, 272 B, 16B-mult)
#define HCS 72                         // Hcol stride (ushorts, 144 B, 16B-mult)
#define HROW_USH (TM * HRS)            // 64*136 = 8704
#define HCOL_USH (128 * HCS)           // 128*72 = 9216
#define TILE_USH (HROW_USH + HCOL_USH) // 17920 ushorts = 35840 B
#define TILE_CHUNKS 35                 // 35840 / 1024

__device__ inline unsigned short f2bf(float x) {
    union { float f; unsigned u; } v; v.f = x;
    unsigned r = v.u + 0x7FFFu + ((v.u >> 16) & 1u);
    return (unsigned short)(r >> 16);
}

// async global->LDS DMA, 16 B/lane, dest = wave-uniform base + lane*16
__device__ inline void dma16(const void* g, void* l) {
    __builtin_amdgcn_global_load_lds(
        (const __attribute__((address_space(1))) void*)g,
        (__attribute__((address_space(3))) void*)l,
        16, 0, 0);
}

// ---- prep (512 blocks = 64 tiles x 8 slices):
//      hidden fp32 -> Hpack[64 tiles][Hrow 64x136 PERMUTED | Hcol 128x72] bf16
//      Hrow row order bit-permuted (phys[b5..b0] = [j2,j5,j4,j3,j1,j0]) so the
//      swapped-QK output lands with j = 32kc+8g+e per lane — PV's A-fragment
//      (P never touches LDS). Identical to R12. ----
__global__ __launch_bounds__(256) void prep_pack_kernel(
    const float* __restrict__ hidden,
    unsigned short* __restrict__ Hpack)
{
    __shared__ unsigned short T[16][HCS];   // transpose slice [d][m]
    const int tid = threadIdx.x;
    const int t0  = blockIdx.x >> 3;   // tile 0..63
    const int s   = blockIdx.x & 7;    // slice 0..7
    const int m0  = t0 * TM;
    unsigned short* rowdst = Hpack + (size_t)t0 * TILE_USH;
    unsigned short* coldst = rowdst + HROW_USH;

    // rows part: logical rows [8s, 8s+8) x 128 d -> permuted physical rows
    {
        int row = tid >> 5;            // 0..7
        int c4  = (tid & 31) * 4;      // 0..124
        int j   = 8 * s + row;         // logical row in tile (0..63)
        int pj  = ((j >> 2) & 1) * 32 + ((j >> 5) & 1) * 16
                + ((j >> 3) & 3) * 4  + (j & 3);          // bijective bit-perm
        float4 v = *(const float4*)(hidden + (size_t)(m0 + j) * DIM + c4);
        ushort4 o;
        o.x = f2bf(v.x); o.y = f2bf(v.y); o.z = f2bf(v.z); o.w = f2bf(v.w);
        *(ushort4*)(rowdst + pj * HRS + c4) = o;
    }
    // cols part: d in [16s, 16s+16) x 64 m -> T (transposed); m-order LINEAR
    {
        int m  = tid >> 2;             // 0..63
        int dc = (tid & 3) * 4;        // 0..12
        float4 v = *(const float4*)(hidden + (size_t)(m0 + m) * DIM + 16 * s + dc);
        T[dc + 0][m] = f2bf(v.x);
        T[dc + 1][m] = f2bf(v.y);
        T[dc + 2][m] = f2bf(v.z);
        T[dc + 3][m] = f2bf(v.w);
    }
    __syncthreads();
    if (tid < 128) {
        int d  = tid >> 3;             // 0..15
        int c8 = (tid & 7) * 8;        // m chunk of 8
        uint4 v = *(const uint4*)(&T[d][c8]);
        *(uint4*)(coldst + (16 * s + d) * HCS + c8) = v;
    }
}

// ---- main (round 13): R12 inner loop VERBATIM, but 8-WAVE (512-thread)
//      BLOCKS sharing one tile: TN=128, NSPLIT=16, grid 512 = 2 blocks/CU
//      -> 16 waves/CU = 4 waves/SIMD (2x R12's TLP). This routes around both
//      mapped failure modes: blocks stay <=2 per CU (R8's dispatcher cap was
//      on BLOCKS), and __launch_bounds__(512,2) is the R0-proven declaration
//      (landed 120 VGPR clean; R12's per-wave state is ~100 <= 128, the HW
//      cap for 4 waves/EU). Bonus: each Hpack tile now serves 128 q-rows ->
//      L2 re-read traffic halves. Cost: 4 tiles/block (prologue fraction
//      up) and 16 atomic adds/cell (WRITE ~33 MB, ~0.8 TB/s). ----
__global__ __launch_bounds__(512, 2) void gat_flash_kernel(
    const float* __restrict__ hidden,        // fp32 (for Q fragments)
    const unsigned short* __restrict__ Hpack,
    const int*   __restrict__ adj,           // [NN][NN] int32
    const float* __restrict__ W,
    const float* __restrict__ bvec,
    float*       __restrict__ Onum,          // [NN][DIM] fp32, pre-zeroed
    float*       __restrict__ lsum)          // [NN] fp32, pre-zeroed
{
    __shared__ __align__(16) unsigned short HH[2][TILE_USH];   // 71680 B (only LDS)

    const int tid  = threadIdx.x;
    const int w    = tid >> 6;         // 0..7: wave = 16-row group
    const int lane = tid & 63;
    const int g    = lane >> 4;
    const int l15  = lane & 15;
    const int blk  = blockIdx.x;
    const int nbr  = blk >> 4;         // 0..31 row-group of 128
    const int q16  = blk & 15;         // 0..15 column sixteenth
    const int n0   = nbr * TN;
    const int gt0  = q16 * NTILES;     // first global tile (of 64)
    const int lofs = lane * 16;

    const float b0 = bvec[0], b1 = bvec[1], b2 = bvec[2], b3 = bvec[3];

    // ---- prologue: DMA tile 0 -> HH[0]; overlaps Af build + adj loads ----
    {
        const char* src = (const char*)(Hpack + (size_t)gt0 * TILE_USH);
        char* dst = (char*)&HH[0][0];
        #pragma unroll
        for (int it = 0; it < 5; ++it) {
            int chunk = it * 8 + w;
            if (chunk < TILE_CHUNKS)
                dma16(src + chunk * 1024 + lofs, dst + chunk * 1024);
        }
    }

    // ---- Af built directly from global (h (.) W_k): B-operand of swapped QK.
    bf16x8 Af[4][4];
    {
        const int qrow = n0 + w * 16 + l15;
        #pragma unroll
        for (int ks = 0; ks < 4; ++ks) {
            const float* hp = hidden + (size_t)qrow * DIM + ks * 32 + 8 * g;
            float4 h0 = *(const float4*)(hp);
            float4 h1 = *(const float4*)(hp + 4);
            #pragma unroll
            for (int k = 0; k < 4; ++k) {
                const float* wp = W + k * DIM + ks * 32 + 8 * g;
                float4 w0 = *(const float4*)(wp);
                float4 w1 = *(const float4*)(wp + 4);
                bf16x8 a;
                a[0] = (short)f2bf(h0.x * w0.x); a[1] = (short)f2bf(h0.y * w0.y);
                a[2] = (short)f2bf(h0.z * w0.z); a[3] = (short)f2bf(h0.w * w0.w);
                a[4] = (short)f2bf(h1.x * w1.x); a[5] = (short)f2bf(h1.y * w1.y);
                a[6] = (short)f2bf(h1.z * w1.z); a[7] = (short)f2bf(h1.w * w1.w);
                Af[k][ks] = a;
            }
        }
    }

    float plsum = 0.f;                 // softmax denom for q = l15 (this lane)
    f32x4 Oacc[8];
    #pragma unroll
    for (int dt = 0; dt < 8; ++dt) Oacc[dt] = (f32x4){0.f, 0.f, 0.f, 0.f};

    // adj codes, tile 0: slice s covers j = 32(s&1) + 8g + 4(s>>1) + 0..3 -> int4
    const int* arow_ptr = adj + (size_t)(n0 + w * 16 + l15) * NN;
    const int joff0 = 8 * g;                          // s=0: kc0,h0
    const int joff1 = 32 + 8 * g;                     // s=1: kc1,h0
    const int joff2 = 8 * g + 4;                      // s=2: kc0,h1
    const int joff3 = 32 + 8 * g + 4;                 // s=3: kc1,h1
    int4 avc[4], avn[4];
    avc[0] = *(const int4*)(arow_ptr + gt0 * TM + joff0);
    avc[1] = *(const int4*)(arow_ptr + gt0 * TM + joff1);
    avc[2] = *(const int4*)(arow_ptr + gt0 * TM + joff2);
    avc[3] = *(const int4*)(arow_ptr + gt0 * TM + joff3);

    __syncthreads();   // drains tile-0 DMA (vmcnt); only barrier before loop

    for (int tile = 0; tile < NTILES; ++tile) {
        const int cur = tile & 1;
        const int nxt = cur ^ 1;

        // ---- issue next-tile DMA; stays in flight all tile ----
        if (tile + 1 < NTILES) {
            const char* src = (const char*)(Hpack + (size_t)(gt0 + tile + 1) * TILE_USH);
            char* dst = (char*)&HH[nxt][0];
            #pragma unroll
            for (int it = 0; it < 5; ++it) {
                int chunk = it * 8 + w;
                if (chunk < TILE_CHUNKS)
                    dma16(src + chunk * 1024 + lofs, dst + chunk * 1024);
            }
        }

        // ---- swapped QK + select + exp per slice; pack into Pa regs ----
        u32x4 paw0, paw1;   // PV A-frag words: kc=0 / kc=1

#define QK_SLICE(S, W0, W1)                                                        \
        {                                                                          \
            f32x4 Sv[4];                                                           \
            _Pragma("unroll")                                                      \
            for (int k = 0; k < 4; ++k) Sv[k] = (f32x4){0.f, 0.f, 0.f, 0.f};       \
            _Pragma("unroll")                                                      \
            for (int ks = 0; ks < 4; ++ks) {                                       \
                bf16x8 Hf = *(const bf16x8*)&HH[cur][((S) * 16 + l15) * HRS + ks * 32 + 8 * g]; \
                _Pragma("unroll")                                                  \
                for (int k = 0; k < 4; ++k)                                        \
                    Sv[k] = __builtin_amdgcn_mfma_f32_16x16x32_bf16(Hf, Af[k][ks], Sv[k], 0, 0, 0); \
            }                                                                      \
            const int4 av = avc[S];                                                \
            float p[4];                                                            \
            _Pragma("unroll")                                                      \
            for (int t = 0; t < 4; ++t) {                                          \
                const int a = (t == 0) ? av.x : (t == 1) ? av.y : (t == 2) ? av.z : av.w; \
                float sc = Sv[0][t] + b0;                                          \
                sc = (a == 2) ? Sv[1][t] + b1 : sc;                                \
                sc = (a == 3) ? Sv[2][t] + b2 : sc;                                \
                sc = (a == 4) ? Sv[3][t] + b3 : sc;                                \
                float e = fmaxf(sc, 0.2f * sc);                                    \
                float pp = __expf(e);          /* no-max softmax; bounded */       \
                pp = (a == 0) ? 0.f : pp;                                          \
                plsum += pp;                                                       \
                p[t] = pp;                                                         \
            }                                                                      \
            unsigned r01, r23;                                                     \
            asm("v_cvt_pk_bf16_f32 %0, %1, %2" : "=v"(r01) : "v"(p[0]), "v"(p[1])); \
            asm("v_cvt_pk_bf16_f32 %0, %1, %2" : "=v"(r23) : "v"(p[2]), "v"(p[3])); \
            W0 = r01; W1 = r23;                                                    \
        }

        QK_SLICE(0, paw0.x, paw0.y)    // kc=0, e=0..3
        QK_SLICE(1, paw1.x, paw1.y)    // kc=1, e=0..3
        QK_SLICE(2, paw0.z, paw0.w)    // kc=0, e=4..7
        QK_SLICE(3, paw1.z, paw1.w)    // kc=1, e=4..7
#undef QK_SLICE

        // ---- adj prefetch for next tile (hidden by PV + next QK) ----
        if (tile + 1 < NTILES) {
            const int* ap = arow_ptr + (gt0 + tile + 1) * TM;
            avn[0] = *(const int4*)(ap + joff0);
            avn[1] = *(const int4*)(ap + joff1);
            avn[2] = *(const int4*)(ap + joff2);
            avn[3] = *(const int4*)(ap + joff3);
        }

        // ---- PV: Pa straight from registers (no LDS round-trip, no lgkm) ----
        {
            bf16x8 Pa0 = __builtin_bit_cast(bf16x8, paw0);
            bf16x8 Pa1 = __builtin_bit_cast(bf16x8, paw1);
            #pragma unroll
            for (int dt = 0; dt < 8; ++dt) {
                bf16x8 Bv0 = *(const bf16x8*)&HH[cur][HROW_USH + (dt * 16 + l15) * HCS + 8 * g];
                Oacc[dt] = __builtin_amdgcn_mfma_f32_16x16x32_bf16(Pa0, Bv0, Oacc[dt], 0, 0, 0);
            }
            #pragma unroll
            for (int dt = 0; dt < 8; ++dt) {
                bf16x8 Bv1 = *(const bf16x8*)&HH[cur][HROW_USH + (dt * 16 + l15) * HCS + 32 + 8 * g];
                Oacc[dt] = __builtin_amdgcn_mfma_f32_16x16x32_bf16(Pa1, Bv1, Oacc[dt], 0, 0, 0);
            }
        }

        #pragma unroll
        for (int i = 0; i < 4; ++i) avc[i] = avn[i];
        __syncthreads();   // vmcnt(0) drain == "HH[nxt] staged"; buffer swap
    }

    // ---- epilogue: q = l15 per lane; sum over the 4 g-groups via shuffles ----
    {
        float v = plsum;
        v += __shfl_xor(v, 16);
        v += __shfl_xor(v, 32);
        if (lane < 16) atomicAdd(&lsum[n0 + w * 16 + l15], v);
    }
    const int orow0 = n0 + w * 16 + 4 * g;
    #pragma unroll
    for (int dt = 0; dt < 8; ++dt)
        #pragma unroll
        for (int t = 0; t < 4; ++t)
            atomicAdd(&Onum[(size_t)(orow0 + t) * DIM + dt * 16 + l15], Oacc[dt][t]);
}

// ---- combine: trivial divide ----
__global__ __launch_bounds__(256) void combine_kernel(
    const float* __restrict__ Onum, const float* __restrict__ lsum,
    float* __restrict__ out)
{
    int idx = blockIdx.x * 256 + threadIdx.x;
    out[idx] = Onum[idx] / lsum[idx >> 7];
}

extern "C" void kernel_launch(void* const* d_in, const int* in_sizes, int n_in,
                              void* d_out, int out_size, void* d_ws, size_t ws_size,
                              hipStream_t stream) {
    const float* hidden = (const float*)d_in[0];
    const int*   adj    = (const int*)d_in[1];
    const float* W      = (const float*)d_in[2];
    const float* b      = (const float*)d_in[3];
    float* out = (float*)d_out;

    char* ws = (char*)d_ws;
    unsigned short* Hpack = (unsigned short*)ws;                 // 2.29 MB
    float* Onum = (float*)(ws + (4u << 20));                     // 2 MB
    float* lsum = (float*)(ws + (6u << 20));                     // 16 KB
    // zero Onum + lsum in one contiguous memset (graph-capturable)
    hipMemsetAsync(ws + (4u << 20), 0, (2u << 20) + NN * sizeof(float), stream);

    prep_pack_kernel<<<(NN / TM) * 8, 256, 0, stream>>>(hidden, Hpack);
    gat_flash_kernel<<<(NN / TN) * NSPLIT, 512, 0, stream>>>(hidden, Hpack, adj, W, b, Onum, lsum);
    combine_kernel<<<NN * DIM / 256, 256, 0, stream>>>(Onum, lsum, out);
}

// Round 14
// 130.256 us; speedup vs baseline: 1.1554x; 1.1554x over previous
//
#include <hip/hip_runtime.h>

#define NN 4096
#define DIM 128
#define TN 64            // q-rows per block (4 waves x 16 rows)
#define TM 64            // m-tile size
#define NSPLIT 8         // split-m factor (atomic combine)
#define NTILES 8         // tiles per block (64 global tiles / 8)

typedef __attribute__((ext_vector_type(8))) short bf16x8;
typedef __attribute__((ext_vector_type(4))) float f32x4;
typedef __attribute__((ext_vector_type(4))) unsigned u32x4;

#define HRS 136                        // Hrow stride (ushorts, 272 B, 16B-mult)
#define HCS 72                         // Hcol stride (ushorts, 144 B, 16B-mult)
#define HROW_USH (TM * HRS)            // 64*136 = 8704
#define HCOL_USH (128 * HCS)           // 128*72 = 9216
#define TILE_USH (HROW_USH + HCOL_USH) // 17920 ushorts = 35840 B
#define TILE_CHUNKS 35                 // 35840 / 1024

__device__ inline unsigned short f2bf(float x) {
    union { float f; unsigned u; } v; v.f = x;
    unsigned r = v.u + 0x7FFFu + ((v.u >> 16) & 1u);
    return (unsigned short)(r >> 16);
}

// async global->LDS DMA, 16 B/lane, dest = wave-uniform base + lane*16
__device__ inline void dma16(const void* g, void* l) {
    __builtin_amdgcn_global_load_lds(
        (const __attribute__((address_space(1))) void*)g,
        (__attribute__((address_space(3))) void*)l,
        16, 0, 0);
}

// ---- prep (512 blocks = 64 tiles x 8 slices):
//      hidden fp32 -> Hpack[64 tiles][Hrow 64x136 PERMUTED | Hcol 128x72] bf16
//      Hrow row order bit-permuted (phys[b5..b0] = [j2,j5,j4,j3,j1,j0]) so the
//      swapped-QK output lands with j = 32kc+8g+e per lane — PV's A-fragment
//      (P never touches LDS). Identical to R12. ----
__global__ __launch_bounds__(256) void prep_pack_kernel(
    const float* __restrict__ hidden,
    unsigned short* __restrict__ Hpack)
{
    __shared__ unsigned short T[16][HCS];   // transpose slice [d][m]
    const int tid = threadIdx.x;
    const int t0  = blockIdx.x >> 3;   // tile 0..63
    const int s   = blockIdx.x & 7;    // slice 0..7
    const int m0  = t0 * TM;
    unsigned short* rowdst = Hpack + (size_t)t0 * TILE_USH;
    unsigned short* coldst = rowdst + HROW_USH;

    // rows part: logical rows [8s, 8s+8) x 128 d -> permuted physical rows
    {
        int row = tid >> 5;            // 0..7
        int c4  = (tid & 31) * 4;      // 0..124
        int j   = 8 * s + row;         // logical row in tile (0..63)
        int pj  = ((j >> 2) & 1) * 32 + ((j >> 5) & 1) * 16
                + ((j >> 3) & 3) * 4  + (j & 3);          // bijective bit-perm
        float4 v = *(const float4*)(hidden + (size_t)(m0 + j) * DIM + c4);
        ushort4 o;
        o.x = f2bf(v.x); o.y = f2bf(v.y); o.z = f2bf(v.z); o.w = f2bf(v.w);
        *(ushort4*)(rowdst + pj * HRS + c4) = o;
    }
    // cols part: d in [16s, 16s+16) x 64 m -> T (transposed); m-order LINEAR
    {
        int m  = tid >> 2;             // 0..63
        int dc = (tid & 3) * 4;        // 0..12
        float4 v = *(const float4*)(hidden + (size_t)(m0 + m) * DIM + 16 * s + dc);
        T[dc + 0][m] = f2bf(v.x);
        T[dc + 1][m] = f2bf(v.y);
        T[dc + 2][m] = f2bf(v.z);
        T[dc + 3][m] = f2bf(v.w);
    }
    __syncthreads();
    if (tid < 128) {
        int d  = tid >> 3;             // 0..15
        int c8 = (tid & 7) * 8;        // m chunk of 8
        uint4 v = *(const uint4*)(&T[d][c8]);
        *(uint4*)(coldst + (16 * s + d) * HCS + c8) = v;
    }
}

// ---- main (round 14): R12 champion (43.0 us) with ONE change — the adj
//      prefetch for tile t+1 moves from between-QK-and-PV to the TILE TOP,
//      issued alongside the DMA. Mechanism: __syncthreads drains vmcnt(0),
//      which includes these HBM-latency (~900 cyc) adj loads; issued after QK
//      they had only PV (~300-500 cyc) to land, so the barrier stalled on
//      them every tile. At the top they get the full QK+PV window. The late
//      placement was an R2-era fix for the 64-VGPR allocator regime; at
//      R12's VGPR=100 the +16 live regs fit the 128 budget.
//      R13 falsified 8-wave blocks (effective residency won't rise; +48%);
//      this stays 4-wave / grid 512 / 2 blocks/CU. Everything else —
//      permuted-Hrow register-resident P, swapped QK, DMA double-buffer,
//      one barrier/tile, atomic combine, numerics — byte-identical to R12.
__global__ __launch_bounds__(256, 2) void gat_flash_kernel(
    const float* __restrict__ hidden,        // fp32 (for Q fragments)
    const unsigned short* __restrict__ Hpack,
    const int*   __restrict__ adj,           // [NN][NN] int32
    const float* __restrict__ W,
    const float* __restrict__ bvec,
    float*       __restrict__ Onum,          // [NN][DIM] fp32, pre-zeroed
    float*       __restrict__ lsum)          // [NN] fp32, pre-zeroed
{
    __shared__ __align__(16) unsigned short HH[2][TILE_USH];   // 71680 B (only LDS)

    const int tid  = threadIdx.x;
    const int w    = tid >> 6;         // 0..3: wave = 16-row group
    const int lane = tid & 63;
    const int g    = lane >> 4;
    const int l15  = lane & 15;
    const int blk  = blockIdx.x;
    const int nbr  = blk >> 3;         // 0..63 row-group of 64
    const int q8   = blk & 7;          // 0..7 column eighth (== XCD id: L2-local)
    const int n0   = nbr * TN;
    const int gt0  = q8 * NTILES;      // first global tile (of 64)
    const int lofs = lane * 16;

    const float b0 = bvec[0], b1 = bvec[1], b2 = bvec[2], b3 = bvec[3];

    // ---- prologue: DMA tile 0 -> HH[0]; overlaps Af build + adj loads ----
    {
        const char* src = (const char*)(Hpack + (size_t)gt0 * TILE_USH);
        char* dst = (char*)&HH[0][0];
        #pragma unroll
        for (int it = 0; it < 9; ++it) {
            int chunk = it * 4 + w;
            if (chunk < TILE_CHUNKS)
                dma16(src + chunk * 1024 + lofs, dst + chunk * 1024);
        }
    }

    // ---- Af built directly from global (h (.) W_k): B-operand of swapped QK.
    bf16x8 Af[4][4];
    {
        const int qrow = n0 + w * 16 + l15;
        #pragma unroll
        for (int ks = 0; ks < 4; ++ks) {
            const float* hp = hidden + (size_t)qrow * DIM + ks * 32 + 8 * g;
            float4 h0 = *(const float4*)(hp);
            float4 h1 = *(const float4*)(hp + 4);
            #pragma unroll
            for (int k = 0; k < 4; ++k) {
                const float* wp = W + k * DIM + ks * 32 + 8 * g;
                float4 w0 = *(const float4*)(wp);
                float4 w1 = *(const float4*)(wp + 4);
                bf16x8 a;
                a[0] = (short)f2bf(h0.x * w0.x); a[1] = (short)f2bf(h0.y * w0.y);
                a[2] = (short)f2bf(h0.z * w0.z); a[3] = (short)f2bf(h0.w * w0.w);
                a[4] = (short)f2bf(h1.x * w1.x); a[5] = (short)f2bf(h1.y * w1.y);
                a[6] = (short)f2bf(h1.z * w1.z); a[7] = (short)f2bf(h1.w * w1.w);
                Af[k][ks] = a;
            }
        }
    }

    float plsum = 0.f;                 // softmax denom for q = l15 (this lane)
    f32x4 Oacc[8];
    #pragma unroll
    for (int dt = 0; dt < 8; ++dt) Oacc[dt] = (f32x4){0.f, 0.f, 0.f, 0.f};

    // adj codes, tile 0: slice s covers j = 32(s&1) + 8g + 4(s>>1) + 0..3 -> int4
    const int* arow_ptr = adj + (size_t)(n0 + w * 16 + l15) * NN;
    const int joff0 = 8 * g;                          // s=0: kc0,h0
    const int joff1 = 32 + 8 * g;                     // s=1: kc1,h0
    const int joff2 = 8 * g + 4;                      // s=2: kc0,h1
    const int joff3 = 32 + 8 * g + 4;                 // s=3: kc1,h1
    int4 avc[4], avn[4];
    avc[0] = *(const int4*)(arow_ptr + gt0 * TM + joff0);
    avc[1] = *(const int4*)(arow_ptr + gt0 * TM + joff1);
    avc[2] = *(const int4*)(arow_ptr + gt0 * TM + joff2);
    avc[3] = *(const int4*)(arow_ptr + gt0 * TM + joff3);

    __syncthreads();   // drains tile-0 DMA (vmcnt); only barrier before loop

    for (int tile = 0; tile < NTILES; ++tile) {
        const int cur = tile & 1;
        const int nxt = cur ^ 1;

        // ---- issue next-tile DMA + adj prefetch at TILE TOP; both have the
        //      full QK+PV window (~1.6K cyc) to land before the vmcnt(0)
        //      drain at this tile's barrier ----
        if (tile + 1 < NTILES) {
            const char* src = (const char*)(Hpack + (size_t)(gt0 + tile + 1) * TILE_USH);
            char* dst = (char*)&HH[nxt][0];
            #pragma unroll
            for (int it = 0; it < 9; ++it) {
                int chunk = it * 4 + w;
                if (chunk < TILE_CHUNKS)
                    dma16(src + chunk * 1024 + lofs, dst + chunk * 1024);
            }
            const int* ap = arow_ptr + (gt0 + tile + 1) * TM;
            avn[0] = *(const int4*)(ap + joff0);
            avn[1] = *(const int4*)(ap + joff1);
            avn[2] = *(const int4*)(ap + joff2);
            avn[3] = *(const int4*)(ap + joff3);
        }

        // ---- swapped QK + select + exp per slice; pack into Pa regs ----
        u32x4 paw0, paw1;   // PV A-frag words: kc=0 / kc=1

#define QK_SLICE(S, W0, W1)                                                        \
        {                                                                          \
            f32x4 Sv[4];                                                           \
            _Pragma("unroll")                                                      \
            for (int k = 0; k < 4; ++k) Sv[k] = (f32x4){0.f, 0.f, 0.f, 0.f};       \
            _Pragma("unroll")                                                      \
            for (int ks = 0; ks < 4; ++ks) {                                       \
                bf16x8 Hf = *(const bf16x8*)&HH[cur][((S) * 16 + l15) * HRS + ks * 32 + 8 * g]; \
                _Pragma("unroll")                                                  \
                for (int k = 0; k < 4; ++k)                                        \
                    Sv[k] = __builtin_amdgcn_mfma_f32_16x16x32_bf16(Hf, Af[k][ks], Sv[k], 0, 0, 0); \
            }                                                                      \
            const int4 av = avc[S];                                                \
            float p[4];                                                            \
            _Pragma("unroll")                                                      \
            for (int t = 0; t < 4; ++t) {                                          \
                const int a = (t == 0) ? av.x : (t == 1) ? av.y : (t == 2) ? av.z : av.w; \
                float sc = Sv[0][t] + b0;                                          \
                sc = (a == 2) ? Sv[1][t] + b1 : sc;                                \
                sc = (a == 3) ? Sv[2][t] + b2 : sc;                                \
                sc = (a == 4) ? Sv[3][t] + b3 : sc;                                \
                float e = fmaxf(sc, 0.2f * sc);                                    \
                float pp = __expf(e);          /* no-max softmax; bounded */       \
                pp = (a == 0) ? 0.f : pp;                                          \
                plsum += pp;                                                       \
                p[t] = pp;                                                         \
            }                                                                      \
            unsigned r01, r23;                                                     \
            asm("v_cvt_pk_bf16_f32 %0, %1, %2" : "=v"(r01) : "v"(p[0]), "v"(p[1])); \
            asm("v_cvt_pk_bf16_f32 %0, %1, %2" : "=v"(r23) : "v"(p[2]), "v"(p[3])); \
            W0 = r01; W1 = r23;                                                    \
        }

        QK_SLICE(0, paw0.x, paw0.y)    // kc=0, e=0..3
        QK_SLICE(1, paw1.x, paw1.y)    // kc=1, e=0..3
        QK_SLICE(2, paw0.z, paw0.w)    // kc=0, e=4..7
        QK_SLICE(3, paw1.z, paw1.w)    // kc=1, e=4..7
#undef QK_SLICE

        // ---- PV: Pa straight from registers (no LDS round-trip, no lgkm) ----
        {
            bf16x8 Pa0 = __builtin_bit_cast(bf16x8, paw0);
            bf16x8 Pa1 = __builtin_bit_cast(bf16x8, paw1);
            #pragma unroll
            for (int dt = 0; dt < 8; ++dt) {
                bf16x8 Bv0 = *(const bf16x8*)&HH[cur][HROW_USH + (dt * 16 + l15) * HCS + 8 * g];
                Oacc[dt] = __builtin_amdgcn_mfma_f32_16x16x32_bf16(Pa0, Bv0, Oacc[dt], 0, 0, 0);
            }
            #pragma unroll
            for (int dt = 0; dt < 8; ++dt) {
                bf16x8 Bv1 = *(const bf16x8*)&HH[cur][HROW_USH + (dt * 16 + l15) * HCS + 32 + 8 * g];
                Oacc[dt] = __builtin_amdgcn_mfma_f32_16x16x32_bf16(Pa1, Bv1, Oacc[dt], 0, 0, 0);
            }
        }

        #pragma unroll
        for (int i = 0; i < 4; ++i) avc[i] = avn[i];
        __syncthreads();   // vmcnt(0) drain == "HH[nxt] staged"; buffer swap
    }

    // ---- epilogue: q = l15 per lane; sum over the 4 g-groups via shuffles ----
    {
        float v = plsum;
        v += __shfl_xor(v, 16);
        v += __shfl_xor(v, 32);
        if (lane < 16) atomicAdd(&lsum[n0 + w * 16 + l15], v);
    }
    const int orow0 = n0 + w * 16 + 4 * g;
    #pragma unroll
    for (int dt = 0; dt < 8; ++dt)
        #pragma unroll
        for (int t = 0; t < 4; ++t)
            atomicAdd(&Onum[(size_t)(orow0 + t) * DIM + dt * 16 + l15], Oacc[dt][t]);
}

// ---- combine: trivial divide ----
__global__ __launch_bounds__(256) void combine_kernel(
    const float* __restrict__ Onum, const float* __restrict__ lsum,
    float* __restrict__ out)
{
    int idx = blockIdx.x * 256 + threadIdx.x;
    out[idx] = Onum[idx] / lsum[idx >> 7];
}

extern "C" void kernel_launch(void* const* d_in, const int* in_sizes, int n_in,
                              void* d_out, int out_size, void* d_ws, size_t ws_size,
                              hipStream_t stream) {
    const float* hidden = (const float*)d_in[0];
    const int*   adj    = (const int*)d_in[1];
    const float* W      = (const float*)d_in[2];
    const float* b      = (const float*)d_in[3];
    float* out = (float*)d_out;

    char* ws = (char*)d_ws;
    unsigned short* Hpack = (unsigned short*)ws;                 // 2.29 MB
    float* Onum = (float*)(ws + (4u << 20));                     // 2 MB
    float* lsum = (float*)(ws + (6u << 20));                     // 16 KB
    // zero Onum + lsum in one contiguous memset (graph-capturable)
    hipMemsetAsync(ws + (4u << 20), 0, (2u << 20) + NN * sizeof(float), stream);

    prep_pack_kernel<<<(NN / TM) * 8, 256, 0, stream>>>(hidden, Hpack);
    gat_flash_kernel<<<(NN / TN) * NSPLIT, 256, 0, stream>>>(hidden, Hpack, adj, W, b, Onum, lsum);
    combine_kernel<<<NN * DIM / 256, 256, 0, stream>>>(Onum, lsum, out);
}